// Round 3
// baseline (51.583 us; speedup 1.0000x reference)
//
#include <hip/hip_runtime.h>

typedef unsigned short ushort_t;
typedef unsigned int uint_t;
typedef __bf16 bf16x8 __attribute__((ext_vector_type(8)));
typedef float f32x4 __attribute__((ext_vector_type(4)));

#define H 256
#define RPB 32      // batch rows per block
#define NBLK 128    // 4096 / RPB

// output layout (f32): [nb 4096][bdot 4096][y 4096*256][yy 4096*64]
#define NB_OFF 0
#define BDOT_OFF 4096
#define Y_OFF 8192
#define YY_OFF (8192 + 4096 * 256)

__device__ __forceinline__ ushort_t f2bf(float x) {
    union { float f; uint_t u; } c; c.f = x;
    uint_t r = (c.u + 0x7FFFu + ((c.u >> 16) & 1u)) >> 16;  // RNE
    return (ushort_t)r;
}
__device__ __forceinline__ float bf2f(ushort_t v) {
    union { uint_t u; float f; } c; c.u = ((uint_t)v) << 16;
    return c.f;
}

// ws layout (ushort/bf16 units)
#define O_W1b  0        // [256][64]   orig
#define O_W1T  16384    // [64][256]
#define O_W2ab 32768    // [256][256]  orig
#define O_W2bb 98304
#define O_W3ab 163840
#define O_W2aT 229376
#define O_W2bT 294912
#define O_W3aT 360448
#define O_W3sb 425984   // [256][64] orig
#define O_W3sT 442368   // [64][256]

__global__ __launch_bounds__(256) void prep_weights(
    const float* __restrict__ w1, const float* __restrict__ w2a,
    const float* __restrict__ w2b, const float* __restrict__ w3a,
    const float* __restrict__ w3s, ushort_t* __restrict__ ws) {
    __shared__ ushort_t tile[64][65];
    int b = blockIdx.x;
    const float* src; int Oo, Ot, R, C, t;
    if (b < 16)      { src = w2a; Oo = O_W2ab; Ot = O_W2aT; R = 256; C = 256; t = b; }
    else if (b < 32) { src = w2b; Oo = O_W2bb; Ot = O_W2bT; R = 256; C = 256; t = b - 16; }
    else if (b < 48) { src = w3a; Oo = O_W3ab; Ot = O_W3aT; R = 256; C = 256; t = b - 32; }
    else if (b < 52) { src = w1;  Oo = O_W1b;  Ot = O_W1T;  R = 256; C = 64;  t = b - 48; }
    else             { src = w3s; Oo = O_W3sb; Ot = O_W3sT; R = 256; C = 64;  t = b - 52; }
    int tr, tc;
    if (C == 256) { tr = t >> 2; tc = t & 3; } else { tr = t; tc = 0; }
    int r0 = tr * 64, c0 = tc * 64;

    union pack8 { ushort_t u[8]; uint4 q; };
    for (int it = threadIdx.x; it < 512; it += 256) {
        int r = it >> 3, c8 = (it & 7) << 3;
        const float* s = src + (r0 + r) * C + c0 + c8;
        pack8 p;
#pragma unroll
        for (int j = 0; j < 8; j++) { p.u[j] = f2bf(s[j]); tile[r][c8 + j] = p.u[j]; }
        *(uint4*)(ws + Oo + (r0 + r) * C + c0 + c8) = p.q;
    }
    __syncthreads();
    for (int it = threadIdx.x; it < 512; it += 256) {
        int cc = it >> 3, r8 = (it & 7) << 3;
        pack8 p;
#pragma unroll
        for (int j = 0; j < 8; j++) p.u[j] = tile[r8 + j][cc];
        *(uint4*)(ws + Ot + (c0 + cc) * R + r0 + r8) = p.q;
    }
}

// ---- MFMA tile helpers. A: bf16 LDS, row stride STRA, col-XOR-swizzled.
// B: bf16 global [n][k] row-major stride STRB. Two row-tiles (rows 0-15, 16-31)
// share every B fragment. All loads of a call are independent -> deep ILP.

template <int KLEN, int STRA, int STRB>
__device__ __forceinline__ void gemm_dual(const ushort_t* sA, const ushort_t* __restrict__ B,
                                          int lane, int n0, int k0, f32x4& acc0, f32x4& acc1) {
    const int row = lane & 15;
    const int kq = (lane >> 4) << 3;
    const int sw = (row & 7) << 3;
    const ushort_t* a0 = sA + row * STRA;
    const ushort_t* a1 = sA + (row + 16) * STRA;
    const ushort_t* bp = B + (n0 + row) * STRB + k0 + kq;
#pragma unroll
    for (int kb = 0; kb < KLEN; kb += 32) {
        int ka = (k0 + kb + kq) ^ sw;
        bf16x8 b  = *(const bf16x8*)(bp + kb);
        bf16x8 x0 = *(const bf16x8*)(a0 + ka);
        bf16x8 x1 = *(const bf16x8*)(a1 + ka);
        acc0 = __builtin_amdgcn_mfma_f32_16x16x32_bf16(x0, b, acc0, 0, 0, 0);
        acc1 = __builtin_amdgcn_mfma_f32_16x16x32_bf16(x1, b, acc1, 0, 0, 0);
    }
}

// one A (2 row-tiles) x two B matrices -> 4 accumulators
template <int KLEN, int STRA, int STRB>
__device__ __forceinline__ void gemm_quad(const ushort_t* sA, const ushort_t* __restrict__ B0,
                                          const ushort_t* __restrict__ B1, int lane, int n0,
                                          f32x4& a00, f32x4& a01, f32x4& a10, f32x4& a11) {
    const int row = lane & 15;
    const int kq = (lane >> 4) << 3;
    const int sw = (row & 7) << 3;
    const ushort_t* a0 = sA + row * STRA;
    const ushort_t* a1 = sA + (row + 16) * STRA;
    const ushort_t* bp0 = B0 + (n0 + row) * STRB + kq;
    const ushort_t* bp1 = B1 + (n0 + row) * STRB + kq;
#pragma unroll
    for (int kb = 0; kb < KLEN; kb += 32) {
        int ka = (kb + kq) ^ sw;
        bf16x8 b0 = *(const bf16x8*)(bp0 + kb);
        bf16x8 b1 = *(const bf16x8*)(bp1 + kb);
        bf16x8 x0 = *(const bf16x8*)(a0 + ka);
        bf16x8 x1 = *(const bf16x8*)(a1 + ka);
        a00 = __builtin_amdgcn_mfma_f32_16x16x32_bf16(x0, b0, a00, 0, 0, 0);
        a01 = __builtin_amdgcn_mfma_f32_16x16x32_bf16(x1, b0, a01, 0, 0, 0);
        a10 = __builtin_amdgcn_mfma_f32_16x16x32_bf16(x0, b1, a10, 0, 0, 0);
        a11 = __builtin_amdgcn_mfma_f32_16x16x32_bf16(x1, b1, a11, 0, 0, 0);
    }
}

// acc_rt = A0[rt]*B0 + A1[rt]*B1  (summed into same accumulators)
template <int KLEN, int STRA, int STRB>
__device__ __forceinline__ void gemm_pairsum(const ushort_t* sA0, const ushort_t* sA1,
                                             const ushort_t* __restrict__ B0,
                                             const ushort_t* __restrict__ B1,
                                             int lane, int n0, f32x4& acc0, f32x4& acc1) {
    const int row = lane & 15;
    const int kq = (lane >> 4) << 3;
    const int sw = (row & 7) << 3;
    const ushort_t* p00 = sA0 + row * STRA;
    const ushort_t* p01 = sA0 + (row + 16) * STRA;
    const ushort_t* p10 = sA1 + row * STRA;
    const ushort_t* p11 = sA1 + (row + 16) * STRA;
    const ushort_t* bp0 = B0 + (n0 + row) * STRB + kq;
    const ushort_t* bp1 = B1 + (n0 + row) * STRB + kq;
#pragma unroll
    for (int kb = 0; kb < KLEN; kb += 32) {
        int ka = (kb + kq) ^ sw;
        bf16x8 b0  = *(const bf16x8*)(bp0 + kb);
        bf16x8 b1  = *(const bf16x8*)(bp1 + kb);
        bf16x8 x00 = *(const bf16x8*)(p00 + ka);
        bf16x8 x01 = *(const bf16x8*)(p01 + ka);
        bf16x8 x10 = *(const bf16x8*)(p10 + ka);
        bf16x8 x11 = *(const bf16x8*)(p11 + ka);
        acc0 = __builtin_amdgcn_mfma_f32_16x16x32_bf16(x00, b0, acc0, 0, 0, 0);
        acc0 = __builtin_amdgcn_mfma_f32_16x16x32_bf16(x10, b1, acc0, 0, 0, 0);
        acc1 = __builtin_amdgcn_mfma_f32_16x16x32_bf16(x01, b0, acc1, 0, 0, 0);
        acc1 = __builtin_amdgcn_mfma_f32_16x16x32_bf16(x11, b1, acc1, 0, 0, 0);
    }
}

// dynamic LDS layout (bytes)
#define SM_X    0        // ushort [32*64]
#define SM_Z    4096     // ushort [32*256]
#define SM_Y    20480
#define SM_Z12  36864
#define SM_Z22  53248
#define SM_Z13  69632
#define SM_Z23  86016
#define SM_XD   102400   // float [2048]
#define SM_FJ1  110592   // float [2048]
#define SM_FJ2  118784   // float [2048]
#define SM_NB   126976   // float [32]
#define SMEM_BYTES 127104

__device__ __forceinline__ int posw(int r, int c) { return r * H + (c ^ ((r & 7) << 3)); }

__global__ __launch_bounds__(1024) void net_main(
    const float* __restrict__ x, const float* __restrict__ xd,
    const float* __restrict__ b1, const float* __restrict__ b2a,
    const float* __restrict__ b2b, const float* __restrict__ b3a,
    const float* __restrict__ b3s, const float* __restrict__ wout,
    const float* __restrict__ scalar, const ushort_t* __restrict__ ws,
    float* __restrict__ out) {
    extern __shared__ __align__(16) char smem[];
    ushort_t* sX   = (ushort_t*)(smem + SM_X);
    ushort_t* sZ   = (ushort_t*)(smem + SM_Z);
    ushort_t* sY   = (ushort_t*)(smem + SM_Y);
    ushort_t* sZ12 = (ushort_t*)(smem + SM_Z12);
    ushort_t* sZ22 = (ushort_t*)(smem + SM_Z22);
    ushort_t* sZ13 = (ushort_t*)(smem + SM_Z13);
    ushort_t* sZ23 = (ushort_t*)(smem + SM_Z23);
    float* sXd  = (float*)(smem + SM_XD);
    float* sFJ1 = (float*)(smem + SM_FJ1);
    float* sFJ2 = (float*)(smem + SM_FJ2);
    float* sNB  = (float*)(smem + SM_NB);

    const int tid = threadIdx.x;
    const int wid = tid >> 6;       // 0..15
    const int lane = tid & 63;
    const int row16 = lane & 15;    // MFMA D column index
    const int rq = lane >> 4;       // MFMA D row = rq*4 + i
    const int R0 = blockIdx.x * RPB;

    // ---- P0: stage x/xdot, write yy, zero accumulators
    float sc = scalar[0];
#pragma unroll
    for (int e = tid; e < RPB * 64; e += 1024) {
        int r = e >> 6, c = e & 63;
        sX[r * 64 + (c ^ ((r & 7) << 3))] = f2bf(x[(R0 + r) * 64 + c]);
        sXd[e] = xd[(R0 + r) * 64 + c];
        out[YY_OFF + (R0 + r) * 64 + c] = sc;
        sFJ1[e] = 0.f;
        sFJ2[e] = 0.f;
    }
    if (tid < RPB) sNB[tid] = 0.f;
    __syncthreads();

    // ---- P1: z = x@W1.T + b1 (y1=z*z)  AND  z2_3 = x@W3s.T + b3s
    for (int t2 = wid; t2 < 32; t2 += 16) {
        int mat = t2 >> 4, nt = t2 & 15;
        f32x4 acc0 = {0.f,0.f,0.f,0.f}, acc1 = {0.f,0.f,0.f,0.f};
        gemm_dual<64, 64, 64>(sX, ws + (mat ? O_W3sb : O_W1b), lane, nt * 16, 0, acc0, acc1);
        int c = nt * 16 + row16;
        if (mat == 0) {
            float bias = b1[c];
#pragma unroll
            for (int i = 0; i < 4; i++) {
                int r = rq * 4 + i;
                float z0 = acc0[i] + bias;
                sZ[posw(r, c)] = f2bf(z0); sY[posw(r, c)] = f2bf(z0 * z0);
                float z1 = acc1[i] + bias;
                sZ[posw(r + 16, c)] = f2bf(z1); sY[posw(r + 16, c)] = f2bf(z1 * z1);
            }
        } else {
            float bias = b3s[c];
#pragma unroll
            for (int i = 0; i < 4; i++) {
                int r = rq * 4 + i;
                sZ23[posw(r, c)] = f2bf(acc0[i] + bias);
                sZ23[posw(r + 16, c)] = f2bf(acc1[i] + bias);
            }
        }
    }
    __syncthreads();

    // ---- P2: z1_2 = y1@W2a.T + b2a ; z2_2 = y1@W2b.T + b2b (shared A)
    {
        int nt = wid;
        f32x4 a00 = {0.f,0.f,0.f,0.f}, a01 = {0.f,0.f,0.f,0.f};
        f32x4 a10 = {0.f,0.f,0.f,0.f}, a11 = {0.f,0.f,0.f,0.f};
        gemm_quad<H, H, H>(sY, ws + O_W2ab, ws + O_W2bb, lane, nt * 16, a00, a01, a10, a11);
        int c = nt * 16 + row16;
        float ba = b2a[c], bb = b2b[c];
#pragma unroll
        for (int i = 0; i < 4; i++) {
            int r = rq * 4 + i;
            sZ12[posw(r, c)] = f2bf(a00[i] + ba);
            sZ22[posw(r, c)] = f2bf(a10[i] + bb);
            sZ12[posw(r + 16, c)] = f2bf(a01[i] + ba);
            sZ22[posw(r + 16, c)] = f2bf(a11[i] + bb);
        }
    }
    __syncthreads();

    // ---- P3: y2 = z1_2 * z2_2 (elementwise; same swizzle all buffers)
    for (int e = tid; e < RPB * H; e += 1024)
        sY[e] = f2bf(bf2f(sZ12[e]) * bf2f(sZ22[e]));
    __syncthreads();

    // ---- P4: z1_3 = y2@W3a.T + b3a; y3 out; u = wo*z1_3, v = wo*z2_3; nb
    {
        int nt = wid;
        f32x4 acc0 = {0.f,0.f,0.f,0.f}, acc1 = {0.f,0.f,0.f,0.f};
        gemm_dual<H, H, H>(sY, ws + O_W3ab, lane, nt * 16, 0, acc0, acc1);
        int c = nt * 16 + row16;
        float bias = b3a[c], wo = wout[c];
#pragma unroll
        for (int i = 0; i < 4; i++) {
            int r = rq * 4 + i, r1 = r + 16;
            int p = posw(r, c), p1 = posw(r1, c);
            float z13a = acc0[i] + bias, z23a = bf2f(sZ23[p]);
            float z13b = acc1[i] + bias, z23b = bf2f(sZ23[p1]);
            float y3a = z13a * z23a, y3b = z13b * z23b;
            out[Y_OFF + (R0 + r) * H + c] = y3a;
            out[Y_OFF + (R0 + r1) * H + c] = y3b;
            sZ13[p] = f2bf(wo * z13a); sZ23[p] = f2bf(wo * z23a);
            sZ13[p1] = f2bf(wo * z13b); sZ23[p1] = f2bf(wo * z23b);
            float v0 = wo * y3a, v1 = wo * y3b;
            v0 += __shfl_xor(v0, 1); v0 += __shfl_xor(v0, 2);
            v0 += __shfl_xor(v0, 4); v0 += __shfl_xor(v0, 8);
            v1 += __shfl_xor(v1, 1); v1 += __shfl_xor(v1, 2);
            v1 += __shfl_xor(v1, 4); v1 += __shfl_xor(v1, 8);
            if (row16 == 0) { atomicAdd(&sNB[r], v0); atomicAdd(&sNB[r1], v1); }
        }
    }
    __syncthreads();

    // ---- P5: t = v@W3aT; fold tz1 = t*z1_2, tz2 = t*z2_2 (in place)
    {
        int nt = wid;
        f32x4 acc0 = {0.f,0.f,0.f,0.f}, acc1 = {0.f,0.f,0.f,0.f};
        gemm_dual<H, H, H>(sZ23, ws + O_W3aT, lane, nt * 16, 0, acc0, acc1);
        int c = nt * 16 + row16;
#pragma unroll
        for (int i = 0; i < 4; i++) {
            int r = rq * 4 + i, r1 = r + 16;
            int p = posw(r, c), p1 = posw(r1, c);
            sZ12[p] = f2bf(acc0[i] * bf2f(sZ12[p]));
            sZ22[p] = f2bf(acc0[i] * bf2f(sZ22[p]));
            sZ12[p1] = f2bf(acc1[i] * bf2f(sZ12[p1]));
            sZ22[p1] = f2bf(acc1[i] * bf2f(sZ22[p1]));
        }
    }
    __syncthreads();

    // ---- P6: p = tz1@W2bT + tz2@W2aT ; c2 = 2*p*z (in place in sZ)
    {
        int nt = wid;
        f32x4 acc0 = {0.f,0.f,0.f,0.f}, acc1 = {0.f,0.f,0.f,0.f};
        gemm_pairsum<H, H, H>(sZ12, sZ22, ws + O_W2bT, ws + O_W2aT, lane, nt * 16, acc0, acc1);
        int c = nt * 16 + row16;
#pragma unroll
        for (int i = 0; i < 4; i++) {
            int r = rq * 4 + i, r1 = r + 16;
            int p = posw(r, c), p1 = posw(r1, c);
            sZ[p] = f2bf(2.f * acc0[i] * bf2f(sZ[p]));
            sZ[p1] = f2bf(2.f * acc1[i] * bf2f(sZ[p1]));
        }
    }
    __syncthreads();

    // ---- P7: fj1 = u@W3sT, fj2 = c2@W1T (N=64, K split in halves)
    {
        int mat = wid & 1, nt = (wid >> 1) & 3, kh = wid >> 3;
        const ushort_t* A = mat ? sZ : sZ13;
        const ushort_t* Bm = ws + (mat ? O_W1T : O_W3sT);
        float* dst = mat ? sFJ2 : sFJ1;
        f32x4 acc0 = {0.f,0.f,0.f,0.f}, acc1 = {0.f,0.f,0.f,0.f};
        gemm_dual<128, H, H>(A, Bm, lane, nt * 16, kh * 128, acc0, acc1);
        int c = nt * 16 + row16;
#pragma unroll
        for (int i = 0; i < 4; i++) {
            atomicAdd(&dst[(rq * 4 + i) * 64 + c], acc0[i]);
            atomicAdd(&dst[(rq * 4 + i + 16) * 64 + c], acc1[i]);
        }
    }
    __syncthreads();

    // ---- P8: bdot + nb writes
    {
        int r = tid >> 5, j = tid & 31;
        float s = (sFJ1[r * 64 + j] + sFJ2[r * 64 + j]) * sXd[r * 64 + j] +
                  (sFJ1[r * 64 + j + 32] + sFJ2[r * 64 + j + 32]) * sXd[r * 64 + j + 32];
        s += __shfl_xor(s, 1, 32);
        s += __shfl_xor(s, 2, 32);
        s += __shfl_xor(s, 4, 32);
        s += __shfl_xor(s, 8, 32);
        s += __shfl_xor(s, 16, 32);
        if (j == 0) out[BDOT_OFF + R0 + r] = s;
        if (tid < RPB) out[NB_OFF + R0 + tid] = sNB[tid];
    }
}

extern "C" void kernel_launch(void* const* d_in, const int* in_sizes, int n_in,
                              void* d_out, int out_size, void* d_ws, size_t ws_size,
                              hipStream_t stream) {
    (void)in_sizes; (void)n_in; (void)out_size; (void)ws_size;
    const float* x = (const float*)d_in[0];
    const float* xd = (const float*)d_in[1];
    const float* w1 = (const float*)d_in[2];
    const float* b1 = (const float*)d_in[3];
    const float* w2a = (const float*)d_in[4];
    const float* b2a = (const float*)d_in[5];
    const float* w2b = (const float*)d_in[6];
    const float* b2b = (const float*)d_in[7];
    const float* w3a = (const float*)d_in[8];
    const float* b3a = (const float*)d_in[9];
    const float* w3s = (const float*)d_in[10];
    const float* b3s = (const float*)d_in[11];
    const float* wout = (const float*)d_in[12];
    const float* scalar = (const float*)d_in[13];
    ushort_t* ws = (ushort_t*)d_ws;
    float* out = (float*)d_out;

    static bool attr_set = false;
    if (!attr_set) {
        hipFuncSetAttribute((const void*)net_main,
                            hipFuncAttributeMaxDynamicSharedMemorySize, SMEM_BYTES);
        attr_set = true;
    }

    prep_weights<<<56, 256, 0, stream>>>(w1, w2a, w2b, w3a, w3s, ws);
    net_main<<<NBLK, 1024, SMEM_BYTES, stream>>>(x, xd, b1, b2a, b2b, b3a, b3s, wout, scalar, ws, out);
}

// Round 4
// 40.314 us; speedup vs baseline: 1.2795x; 1.2795x over previous
//
#include <hip/hip_runtime.h>

typedef unsigned short ushort_t;
typedef unsigned int uint_t;
typedef __bf16 bf16x8 __attribute__((ext_vector_type(8)));
typedef float f32x4 __attribute__((ext_vector_type(4)));

#define H 256
#define RPB 16      // batch rows per block
#define NBLK 256    // 4096 / RPB

// output layout (f32): [nb 4096][bdot 4096][y 4096*256][yy 4096*64]
#define NB_OFF 0
#define BDOT_OFF 4096
#define Y_OFF 8192
#define YY_OFF (8192 + 4096 * 256)

__device__ __forceinline__ ushort_t f2bf(float x) {
    union { float f; uint_t u; } c; c.f = x;
    uint_t r = (c.u + 0x7FFFu + ((c.u >> 16) & 1u)) >> 16;  // RNE
    return (ushort_t)r;
}
__device__ __forceinline__ float bf2f(ushort_t v) {
    union { uint_t u; float f; } c; c.u = ((uint_t)v) << 16;
    return c.f;
}

// ws layout (ushort/bf16 units)
#define O_W1b  0        // [256][64]   orig (B for z)
#define O_W1T  16384    // [64][256]   W1T[i][g] = w1[g][i]
#define O_W2ab 32768    // [256][256]  orig
#define O_W2bb 98304
#define O_W3ab 163840
#define O_W2aT 229376   // [g][h] = w2a[h][g]
#define O_W2bT 294912
#define O_W3aT 360448   // [g][o] = wout[o]*w3a[o][g]   (wout folded!)
#define O_W3sb 425984   // [256][64] orig
#define O_W3sT 442368   // [i][o] = wout[o]*w3s[o][i]   (wout folded!)

__global__ __launch_bounds__(256) void prep_weights(
    const float* __restrict__ w1, const float* __restrict__ w2a,
    const float* __restrict__ w2b, const float* __restrict__ w3a,
    const float* __restrict__ w3s, const float* __restrict__ wout,
    ushort_t* __restrict__ ws) {
    __shared__ float tile[64][65];
    int b = blockIdx.x;
    const float* src; int Oo, Ot, R, C, t; bool scl;
    if (b < 16)      { src = w2a; Oo = O_W2ab; Ot = O_W2aT; R = 256; C = 256; t = b;      scl = false; }
    else if (b < 32) { src = w2b; Oo = O_W2bb; Ot = O_W2bT; R = 256; C = 256; t = b - 16; scl = false; }
    else if (b < 48) { src = w3a; Oo = O_W3ab; Ot = O_W3aT; R = 256; C = 256; t = b - 32; scl = true;  }
    else if (b < 52) { src = w1;  Oo = O_W1b;  Ot = O_W1T;  R = 256; C = 64;  t = b - 48; scl = false; }
    else             { src = w3s; Oo = O_W3sb; Ot = O_W3sT; R = 256; C = 64;  t = b - 52; scl = true;  }
    int tr, tc;
    if (C == 256) { tr = t >> 2; tc = t & 3; } else { tr = t; tc = 0; }
    int r0 = tr * 64, c0 = tc * 64;

    union pack8 { ushort_t u[8]; uint4 q; };
    for (int it = threadIdx.x; it < 512; it += 256) {
        int r = it >> 3, c8 = (it & 7) << 3;
        const float* s = src + (r0 + r) * C + c0 + c8;
        pack8 p;
#pragma unroll
        for (int j = 0; j < 8; j++) { float v = s[j]; tile[r][c8 + j] = v; p.u[j] = f2bf(v); }
        *(uint4*)(ws + Oo + (r0 + r) * C + c0 + c8) = p.q;
    }
    __syncthreads();
    for (int it = threadIdx.x; it < 512; it += 256) {
        int cc = it >> 3, r8 = (it & 7) << 3;
        pack8 p;
#pragma unroll
        for (int j = 0; j < 8; j++) {
            float v = tile[r8 + j][cc];
            if (scl) v *= wout[r0 + r8 + j];
            p.u[j] = f2bf(v);
        }
        *(uint4*)(ws + Ot + (c0 + cc) * R + r0 + r8) = p.q;
    }
}

// ---- MFMA helpers: all loads batched into register arrays BEFORE any MFMA
// (deep ILP: one L2 round-trip amortized over all fragments).
// A: bf16 LDS [16][STRA], col-XOR-swizzled (c ^ ((r&7)<<3)).
// B0/B1: bf16 global, [n][k] row-major stride STRB, base already offset to ntile.

template <int NF, int STRA, int STRB>
__device__ __forceinline__ void gemm2(const ushort_t* sA,
                                      const ushort_t* __restrict__ B0,
                                      const ushort_t* __restrict__ B1,
                                      int lane, f32x4& acc0, f32x4& acc1) {
    const int row = lane & 15;
    const int kq = (lane >> 4) << 3;
    const int sw = (row & 7) << 3;
    bf16x8 bf[2 * NF];
    const ushort_t* bp0 = B0 + row * STRB + kq;
    const ushort_t* bp1 = B1 + row * STRB + kq;
#pragma unroll
    for (int i = 0; i < NF; i++) {
        bf[i] = *(const bf16x8*)(bp0 + i * 32);
        bf[NF + i] = *(const bf16x8*)(bp1 + i * 32);
    }
    bf16x8 af[NF];
    const ushort_t* ap = sA + row * STRA;
#pragma unroll
    for (int i = 0; i < NF; i++) af[i] = *(const bf16x8*)(ap + ((i * 32 + kq) ^ sw));
#pragma unroll
    for (int i = 0; i < NF; i++) {
        acc0 = __builtin_amdgcn_mfma_f32_16x16x32_bf16(af[i], bf[i], acc0, 0, 0, 0);
        acc1 = __builtin_amdgcn_mfma_f32_16x16x32_bf16(af[i], bf[NF + i], acc1, 0, 0, 0);
    }
}

template <int NF, int STRA, int STRB>
__device__ __forceinline__ void gemm1(const ushort_t* sA,
                                      const ushort_t* __restrict__ B0,
                                      int lane, f32x4& acc) {
    const int row = lane & 15;
    const int kq = (lane >> 4) << 3;
    const int sw = (row & 7) << 3;
    bf16x8 bf[NF];
    const ushort_t* bp0 = B0 + row * STRB + kq;
#pragma unroll
    for (int i = 0; i < NF; i++) bf[i] = *(const bf16x8*)(bp0 + i * 32);
    bf16x8 af[NF];
    const ushort_t* ap = sA + row * STRA;
#pragma unroll
    for (int i = 0; i < NF; i++) af[i] = *(const bf16x8*)(ap + ((i * 32 + kq) ^ sw));
#pragma unroll
    for (int i = 0; i < NF; i++)
        acc = __builtin_amdgcn_mfma_f32_16x16x32_bf16(af[i], bf[i], acc, 0, 0, 0);
}

__device__ __forceinline__ int posw(int r, int c) { return r * H + (c ^ ((r & 7) << 3)); }

__global__ __launch_bounds__(512, 2) void net_main(
    const float* __restrict__ x, const float* __restrict__ xd,
    const float* __restrict__ b1, const float* __restrict__ b2a,
    const float* __restrict__ b2b, const float* __restrict__ b3a,
    const float* __restrict__ b3s, const float* __restrict__ wout,
    const float* __restrict__ scalar, const ushort_t* __restrict__ ws,
    float* __restrict__ out) {
    __shared__ __align__(16) ushort_t sX[RPB * 64];   // bf16 x, swizzled
    __shared__ __align__(16) ushort_t sZ[RPB * H];    // z -> c2 = 2*p*z
    __shared__ __align__(16) ushort_t sY[RPB * H];    // y1
    __shared__ __align__(16) ushort_t sZ12[RPB * H];  // z1_2 -> t*z1_2
    __shared__ __align__(16) ushort_t sZ22[RPB * H];  // z2_2 -> t*z2_2
    __shared__ __align__(16) ushort_t sZ13[RPB * H];  // z1_3 (raw)
    __shared__ __align__(16) ushort_t sZ23[RPB * H];  // z2_3 (raw)
    __shared__ __align__(16) ushort_t sU[RPB * H];    // y2 (P2-P4), then FJ f32[2][16][64] (P7+)
    __shared__ __align__(16) float sXd[RPB * 64];
    __shared__ float sNB[RPB];

    const int tid = threadIdx.x;
    const int wid = tid >> 6;     // 0..7
    const int lane = tid & 63;
    const int row16 = lane & 15;  // MFMA D column-within-tile
    const int rq = lane >> 4;     // MFMA D row = rq*4 + i
    const int R0 = blockIdx.x * RPB;
    const int n0 = wid * 32;      // this wave's ntile pair: cols [n0,n0+16), [n0+16,n0+32)
    const int row = lane & 15;
    const int kq = (lane >> 4) << 3;
    const int sw = (row & 7) << 3;

    // ---- P0: prefetch P1 B-fragments; stage x/xd; yy; zero nb
    bf16x8 pb[8];
    {
        const ushort_t* w1p = ws + O_W1b + (n0 + row) * 64 + kq;
        const ushort_t* w3p = ws + O_W3sb + (n0 + row) * 64 + kq;
        pb[0] = *(const bf16x8*)(w1p);
        pb[1] = *(const bf16x8*)(w1p + 32);
        pb[2] = *(const bf16x8*)(w1p + 16 * 64);
        pb[3] = *(const bf16x8*)(w1p + 16 * 64 + 32);
        pb[4] = *(const bf16x8*)(w3p);
        pb[5] = *(const bf16x8*)(w3p + 32);
        pb[6] = *(const bf16x8*)(w3p + 16 * 64);
        pb[7] = *(const bf16x8*)(w3p + 16 * 64 + 32);
    }
    float sc = scalar[0];
#pragma unroll
    for (int e = tid; e < RPB * 64; e += 512) {
        int r = e >> 6, c = e & 63;
        sX[r * 64 + (c ^ ((r & 7) << 3))] = f2bf(x[(R0 + r) * 64 + c]);
        sXd[e] = xd[(R0 + r) * 64 + c];
        out[YY_OFF + (R0 + r) * 64 + c] = sc;
    }
    if (tid < RPB) sNB[tid] = 0.f;
    __syncthreads();

    // ---- P1: z = x@W1.T + b1 (and y1 = z*z); z2_3 = x@W3s.T + b3s
    {
        bf16x8 af0 = *(const bf16x8*)(sX + row * 64 + (kq ^ sw));
        bf16x8 af1 = *(const bf16x8*)(sX + row * 64 + ((32 + kq) ^ sw));
        f32x4 z0 = {0.f,0.f,0.f,0.f}, z1 = {0.f,0.f,0.f,0.f};
        f32x4 q0 = {0.f,0.f,0.f,0.f}, q1 = {0.f,0.f,0.f,0.f};
        z0 = __builtin_amdgcn_mfma_f32_16x16x32_bf16(af0, pb[0], z0, 0, 0, 0);
        z0 = __builtin_amdgcn_mfma_f32_16x16x32_bf16(af1, pb[1], z0, 0, 0, 0);
        z1 = __builtin_amdgcn_mfma_f32_16x16x32_bf16(af0, pb[2], z1, 0, 0, 0);
        z1 = __builtin_amdgcn_mfma_f32_16x16x32_bf16(af1, pb[3], z1, 0, 0, 0);
        q0 = __builtin_amdgcn_mfma_f32_16x16x32_bf16(af0, pb[4], q0, 0, 0, 0);
        q0 = __builtin_amdgcn_mfma_f32_16x16x32_bf16(af1, pb[5], q0, 0, 0, 0);
        q1 = __builtin_amdgcn_mfma_f32_16x16x32_bf16(af0, pb[6], q1, 0, 0, 0);
        q1 = __builtin_amdgcn_mfma_f32_16x16x32_bf16(af1, pb[7], q1, 0, 0, 0);
        int c0 = n0 + row16, c1 = c0 + 16;
        float bz0 = b1[c0], bz1 = b1[c1], bs0 = b3s[c0], bs1 = b3s[c1];
#pragma unroll
        for (int i = 0; i < 4; i++) {
            int r = rq * 4 + i;
            int p0 = posw(r, c0), p1 = posw(r, c1);
            float za = z0[i] + bz0, zb = z1[i] + bz1;
            sZ[p0] = f2bf(za); sY[p0] = f2bf(za * za);
            sZ[p1] = f2bf(zb); sY[p1] = f2bf(zb * zb);
            sZ23[p0] = f2bf(q0[i] + bs0);
            sZ23[p1] = f2bf(q1[i] + bs1);
        }
    }
    __syncthreads();

    // ---- P2: z1_2 = y1@W2a.T + b2a ; z2_2 = y1@W2b.T + b2b ; y2 -> sU
    {
        f32x4 a0 = {0.f,0.f,0.f,0.f}, a1 = {0.f,0.f,0.f,0.f};
        f32x4 c0a = {0.f,0.f,0.f,0.f}, c1a = {0.f,0.f,0.f,0.f};
        gemm2<8, H, H>(sY, ws + O_W2ab + n0 * H, ws + O_W2ab + (n0 + 16) * H, lane, a0, a1);
        gemm2<8, H, H>(sY, ws + O_W2bb + n0 * H, ws + O_W2bb + (n0 + 16) * H, lane, c0a, c1a);
        int c0 = n0 + row16, c1 = c0 + 16;
        float ba0 = b2a[c0], ba1 = b2a[c1], bb0 = b2b[c0], bb1 = b2b[c1];
#pragma unroll
        for (int i = 0; i < 4; i++) {
            int r = rq * 4 + i;
            int p0 = posw(r, c0), p1 = posw(r, c1);
            float z12a = a0[i] + ba0, z22a = c0a[i] + bb0;
            float z12b = a1[i] + ba1, z22b = c1a[i] + bb1;
            sZ12[p0] = f2bf(z12a); sZ22[p0] = f2bf(z22a); sU[p0] = f2bf(z12a * z22a);
            sZ12[p1] = f2bf(z12b); sZ22[p1] = f2bf(z22b); sU[p1] = f2bf(z12b * z22b);
        }
    }
    __syncthreads();

    // ---- P4: z1_3 = y2@W3a.T + b3a  AND  t = z2_3@(wout.w3a)T   [same phase!]
    //          epilogue: y3 out, nb, sZ13=z1_3, fold sZ12*=t, sZ22*=t
    {
        f32x4 z0 = {0.f,0.f,0.f,0.f}, z1 = {0.f,0.f,0.f,0.f};
        f32x4 t0 = {0.f,0.f,0.f,0.f}, t1 = {0.f,0.f,0.f,0.f};
        gemm2<8, H, H>(sU, ws + O_W3ab + n0 * H, ws + O_W3ab + (n0 + 16) * H, lane, z0, z1);
        gemm2<8, H, H>(sZ23, ws + O_W3aT + n0 * H, ws + O_W3aT + (n0 + 16) * H, lane, t0, t1);
        int c0 = n0 + row16, c1 = c0 + 16;
        float ba0 = b3a[c0], ba1 = b3a[c1];
        float wo0 = wout[c0], wo1 = wout[c1];
#pragma unroll
        for (int i = 0; i < 4; i++) {
            int r = rq * 4 + i;
            int p0 = posw(r, c0), p1 = posw(r, c1);
            float z13a = z0[i] + ba0, z23a = bf2f(sZ23[p0]);
            float z13b = z1[i] + ba1, z23b = bf2f(sZ23[p1]);
            float y3a = z13a * z23a, y3b = z13b * z23b;
            out[Y_OFF + (R0 + r) * H + c0] = y3a;
            out[Y_OFF + (R0 + r) * H + c1] = y3b;
            sZ13[p0] = f2bf(z13a);
            sZ13[p1] = f2bf(z13b);
            sZ12[p0] = f2bf(t0[i] * bf2f(sZ12[p0]));
            sZ22[p0] = f2bf(t0[i] * bf2f(sZ22[p0]));
            sZ12[p1] = f2bf(t1[i] * bf2f(sZ12[p1]));
            sZ22[p1] = f2bf(t1[i] * bf2f(sZ22[p1]));
            float v = wo0 * y3a + wo1 * y3b;
            v += __shfl_xor(v, 1);
            v += __shfl_xor(v, 2);
            v += __shfl_xor(v, 4);
            v += __shfl_xor(v, 8);
            if (row16 == 0) atomicAdd(&sNB[r], v);
        }
    }
    __syncthreads();

    // ---- P6: p = tz1@W2bT + tz2@W2aT ; c2 = 2*p*z (in place in sZ)
    {
        f32x4 p0a = {0.f,0.f,0.f,0.f}, p1a = {0.f,0.f,0.f,0.f};
        gemm2<8, H, H>(sZ12, ws + O_W2bT + n0 * H, ws + O_W2bT + (n0 + 16) * H, lane, p0a, p1a);
        gemm2<8, H, H>(sZ22, ws + O_W2aT + n0 * H, ws + O_W2aT + (n0 + 16) * H, lane, p0a, p1a);
        int c0 = n0 + row16, c1 = c0 + 16;
#pragma unroll
        for (int i = 0; i < 4; i++) {
            int r = rq * 4 + i;
            int p0 = posw(r, c0), p1 = posw(r, c1);
            sZ[p0] = f2bf(2.f * p0a[i] * bf2f(sZ[p0]));
            sZ[p1] = f2bf(2.f * p1a[i] * bf2f(sZ[p1]));
        }
    }
    __syncthreads();

    // ---- P7: fj1 = z1_3@(wout.w3s)T (waves 0-3), fj2 = c2@W1T (waves 4-7)
    {
        int mat = wid >> 2;  // 0: fj1, 1: fj2
        int nt = wid & 3;
        const ushort_t* A = mat ? sZ : sZ13;
        const ushort_t* B = ws + (mat ? O_W1T : O_W3sT) + nt * 16 * H;
        f32x4 acc = {0.f,0.f,0.f,0.f};
        gemm1<8, H, H>(A, B, lane, acc);
        float* dst = (float*)sU + mat * 1024;  // sU reused: fj1 | fj2, f32 [16][64]
        int c = nt * 16 + row16;
#pragma unroll
        for (int i = 0; i < 4; i++) dst[(rq * 4 + i) * 64 + c] = acc[i];
    }
    __syncthreads();

    // ---- P8: bdot + nb writes
    {
        float* sFJ1 = (float*)sU;
        float* sFJ2 = sFJ1 + 1024;
        int r = tid >> 5, j = tid & 31;
        float s = (sFJ1[r * 64 + j] + sFJ2[r * 64 + j]) * sXd[r * 64 + j] +
                  (sFJ1[r * 64 + j + 32] + sFJ2[r * 64 + j + 32]) * sXd[r * 64 + j + 32];
        s += __shfl_xor(s, 1, 32);
        s += __shfl_xor(s, 2, 32);
        s += __shfl_xor(s, 4, 32);
        s += __shfl_xor(s, 8, 32);
        s += __shfl_xor(s, 16, 32);
        if (j == 0) out[BDOT_OFF + R0 + r] = s;
        if (tid < RPB) out[NB_OFF + R0 + tid] = sNB[tid];
    }
}

extern "C" void kernel_launch(void* const* d_in, const int* in_sizes, int n_in,
                              void* d_out, int out_size, void* d_ws, size_t ws_size,
                              hipStream_t stream) {
    (void)in_sizes; (void)n_in; (void)out_size; (void)ws_size;
    const float* x = (const float*)d_in[0];
    const float* xd = (const float*)d_in[1];
    const float* w1 = (const float*)d_in[2];
    const float* b1 = (const float*)d_in[3];
    const float* w2a = (const float*)d_in[4];
    const float* b2a = (const float*)d_in[5];
    const float* w2b = (const float*)d_in[6];
    const float* b2b = (const float*)d_in[7];
    const float* w3a = (const float*)d_in[8];
    const float* b3a = (const float*)d_in[9];
    const float* w3s = (const float*)d_in[10];
    const float* b3s = (const float*)d_in[11];
    const float* wout = (const float*)d_in[12];
    const float* scalar = (const float*)d_in[13];
    ushort_t* ws = (ushort_t*)d_ws;
    float* out = (float*)d_out;

    prep_weights<<<56, 256, 0, stream>>>(w1, w2a, w2b, w3a, w3s, wout, ws);
    net_main<<<NBLK, 512, 0, stream>>>(x, xd, b1, b2a, b2b, b3a, b3s, wout, scalar, ws, out);
}

// Round 5
// 39.200 us; speedup vs baseline: 1.3159x; 1.0284x over previous
//
#include <hip/hip_runtime.h>

typedef unsigned short ushort_t;
typedef unsigned int uint_t;
typedef __bf16 bf16x8 __attribute__((ext_vector_type(8)));
typedef float f32x4 __attribute__((ext_vector_type(4)));

#define H 256
#define RPB 16      // batch rows per block
#define NBLK 256    // 4096 / RPB

// output layout (f32): [nb 4096][bdot 4096][y 4096*256][yy 4096*64]
#define NB_OFF 0
#define BDOT_OFF 4096
#define Y_OFF 8192
#define YY_OFF (8192 + 4096 * 256)

__device__ __forceinline__ ushort_t f2bf(float x) {
    union { float f; uint_t u; } c; c.f = x;
    uint_t r = (c.u + 0x7FFFu + ((c.u >> 16) & 1u)) >> 16;  // RNE
    return (ushort_t)r;
}
__device__ __forceinline__ float bf2f(ushort_t v) {
    union { uint_t u; float f; } c; c.u = ((uint_t)v) << 16;
    return c.f;
}

// ws layout (ushort/bf16 units)
#define O_W1b  0        // [256][64]   orig (B for z)
#define O_W1T  16384    // [64][256]   W1T[i][g] = w1[g][i]
#define O_W2ab 32768    // [256][256]  orig
#define O_W2bb 98304
#define O_W3ab 163840
#define O_W2aT 229376   // [g][h] = w2a[h][g]
#define O_W2bT 294912
#define O_W3aT 360448   // [g][o] = wout[o]*w3a[o][g]   (wout folded)
#define O_W3sb 425984   // [256][64] orig
#define O_W3sT 442368   // [i][o] = wout[o]*w3s[o][i]   (wout folded)

__global__ __launch_bounds__(256) void prep_weights(
    const float* __restrict__ w1, const float* __restrict__ w2a,
    const float* __restrict__ w2b, const float* __restrict__ w3a,
    const float* __restrict__ w3s, const float* __restrict__ wout,
    ushort_t* __restrict__ ws) {
    __shared__ float tile[64][65];
    int b = blockIdx.x;
    const float* src; int Oo, Ot, R, C, t; bool scl;
    if (b < 16)      { src = w2a; Oo = O_W2ab; Ot = O_W2aT; R = 256; C = 256; t = b;      scl = false; }
    else if (b < 32) { src = w2b; Oo = O_W2bb; Ot = O_W2bT; R = 256; C = 256; t = b - 16; scl = false; }
    else if (b < 48) { src = w3a; Oo = O_W3ab; Ot = O_W3aT; R = 256; C = 256; t = b - 32; scl = true;  }
    else if (b < 52) { src = w1;  Oo = O_W1b;  Ot = O_W1T;  R = 256; C = 64;  t = b - 48; scl = false; }
    else             { src = w3s; Oo = O_W3sb; Ot = O_W3sT; R = 256; C = 64;  t = b - 52; scl = true;  }
    int tr, tc;
    if (C == 256) { tr = t >> 2; tc = t & 3; } else { tr = t; tc = 0; }
    int r0 = tr * 64, c0 = tc * 64;

    union pack8 { ushort_t u[8]; uint4 q; };
    for (int it = threadIdx.x; it < 512; it += 256) {
        int r = it >> 3, c8 = (it & 7) << 3;
        const float* s = src + (r0 + r) * C + c0 + c8;
        pack8 p;
#pragma unroll
        for (int j = 0; j < 8; j++) { float v = s[j]; tile[r][c8 + j] = v; p.u[j] = f2bf(v); }
        *(uint4*)(ws + Oo + (r0 + r) * C + c0 + c8) = p.q;
    }
    __syncthreads();
    for (int it = threadIdx.x; it < 512; it += 256) {
        int cc = it >> 3, r8 = (it & 7) << 3;
        pack8 p;
#pragma unroll
        for (int j = 0; j < 8; j++) {
            float v = tile[r8 + j][cc];
            if (scl) v *= wout[r0 + r8 + j];
            p.u[j] = f2bf(v);
        }
        *(uint4*)(ws + Ot + (c0 + cc) * R + r0 + r8) = p.q;
    }
}

// ---- MFMA helpers. Loads are clustered and PINNED before the MFMAs with
// sched_barrier(0) so the LLVM scheduler cannot serialize them just-in-time.
// A: bf16 LDS [16][STRA], col-XOR-swizzled (c ^ ((r&7)<<3)).
// B: bf16 global [n][k] row-major stride STRB, base pre-offset to the n-tile.

template <int NF, int STRA, int STRB>
__device__ __forceinline__ void gemm_one(const ushort_t* sA, const ushort_t* __restrict__ B0,
                                         int lane, int k0, f32x4& acc0) {
    const int row = lane & 15;
    const int kq = (lane >> 4) << 3;
    const int sw = (row & 7) << 3;
    bf16x8 b0[NF], a[NF];
    const ushort_t* bp0 = B0 + row * STRB + k0 + kq;
    const ushort_t* ap = sA + row * STRA;
#pragma unroll
    for (int i = 0; i < NF; i++) b0[i] = *(const bf16x8*)(bp0 + i * 32);
#pragma unroll
    for (int i = 0; i < NF; i++) a[i] = *(const bf16x8*)(ap + ((k0 + i * 32 + kq) ^ sw));
    __builtin_amdgcn_sched_barrier(0);
#pragma unroll
    for (int i = 0; i < NF; i++)
        acc0 = __builtin_amdgcn_mfma_f32_16x16x32_bf16(a[i], b0[i], acc0, 0, 0, 0);
}

// shared A, two B matrices -> two accumulators (24 fragments live)
template <int NF, int STRA, int STRB>
__device__ __forceinline__ void gemm_dualB(const ushort_t* sA,
                                           const ushort_t* __restrict__ B0,
                                           const ushort_t* __restrict__ B1,
                                           int lane, f32x4& acc0, f32x4& acc1) {
    const int row = lane & 15;
    const int kq = (lane >> 4) << 3;
    const int sw = (row & 7) << 3;
    bf16x8 b0[NF], b1[NF], a[NF];
    const ushort_t* bp0 = B0 + row * STRB + kq;
    const ushort_t* bp1 = B1 + row * STRB + kq;
    const ushort_t* ap = sA + row * STRA;
#pragma unroll
    for (int i = 0; i < NF; i++) b0[i] = *(const bf16x8*)(bp0 + i * 32);
#pragma unroll
    for (int i = 0; i < NF; i++) b1[i] = *(const bf16x8*)(bp1 + i * 32);
#pragma unroll
    for (int i = 0; i < NF; i++) a[i] = *(const bf16x8*)(ap + ((i * 32 + kq) ^ sw));
    __builtin_amdgcn_sched_barrier(0);
#pragma unroll
    for (int i = 0; i < NF; i++) {
        acc0 = __builtin_amdgcn_mfma_f32_16x16x32_bf16(a[i], b0[i], acc0, 0, 0, 0);
        acc1 = __builtin_amdgcn_mfma_f32_16x16x32_bf16(a[i], b1[i], acc1, 0, 0, 0);
    }
}

__device__ __forceinline__ int posw(int r, int c) { return r * H + (c ^ ((r & 7) << 3)); }

__global__ __launch_bounds__(1024) void net_main(
    const float* __restrict__ x, const float* __restrict__ xd,
    const float* __restrict__ b1, const float* __restrict__ b2a,
    const float* __restrict__ b2b, const float* __restrict__ b3a,
    const float* __restrict__ b3s, const float* __restrict__ wout,
    const float* __restrict__ scalar, const ushort_t* __restrict__ ws,
    float* __restrict__ out) {
    __shared__ __align__(16) ushort_t sX[RPB * 64];   // bf16 x, swizzled
    __shared__ __align__(16) ushort_t sZ[RPB * H];    // z -> c2 = 2*p*z
    __shared__ __align__(16) ushort_t sY[RPB * H];    // y1; later FJ[0..1] f32
    __shared__ __align__(16) ushort_t sZ12[RPB * H];  // z1_2 -> t*z1_2
    __shared__ __align__(16) ushort_t sZ22[RPB * H];  // z2_2 -> t*z2_2
    __shared__ __align__(16) ushort_t sZ13[RPB * H];  // z1_3 (raw)
    __shared__ __align__(16) ushort_t sZ23[RPB * H];  // z2_3 (raw)
    __shared__ __align__(16) ushort_t sU[RPB * H];    // y2; later FJ[2..3] f32
    __shared__ __align__(16) float sXd[RPB * 64];
    __shared__ float sNB[RPB];

    const int tid = threadIdx.x;
    const int wid = tid >> 6;     // 0..15
    const int lane = tid & 63;
    const int row16 = lane & 15;  // MFMA D column-within-tile
    const int rq = lane >> 4;     // MFMA D row = rq*4 + i
    const int R0 = blockIdx.x * RPB;
    const int n0 = wid * 16;      // this wave's 16-col tile
    const int row = lane & 15;
    const int kq = (lane >> 4) << 3;
    const int sw = (row & 7) << 3;

    // ---- P0: prefetch P1 B-fragments; stage x/xd; yy; zero nb
    bf16x8 pb0, pb1, pb2, pb3;
    {
        const ushort_t* w1p = ws + O_W1b + (n0 + row) * 64 + kq;
        const ushort_t* w3p = ws + O_W3sb + (n0 + row) * 64 + kq;
        pb0 = *(const bf16x8*)(w1p);
        pb1 = *(const bf16x8*)(w1p + 32);
        pb2 = *(const bf16x8*)(w3p);
        pb3 = *(const bf16x8*)(w3p + 32);
    }
    float sc = scalar[0];
    {
        int r = tid >> 6, c = tid & 63;  // 1024 threads = RPB*64 elements
        sX[r * 64 + (c ^ ((r & 7) << 3))] = f2bf(x[(R0 + r) * 64 + c]);
        sXd[tid] = xd[(R0 + r) * 64 + c];
        out[YY_OFF + (R0 + r) * 64 + c] = sc;
    }
    if (tid < RPB) sNB[tid] = 0.f;
    __syncthreads();

    // ---- P1: z = x@W1.T + b1 (y1 = z*z); z2_3 = x@W3s.T + b3s
    {
        bf16x8 af0 = *(const bf16x8*)(sX + row * 64 + (kq ^ sw));
        bf16x8 af1 = *(const bf16x8*)(sX + row * 64 + ((32 + kq) ^ sw));
        f32x4 z = {0.f,0.f,0.f,0.f}, q = {0.f,0.f,0.f,0.f};
        z = __builtin_amdgcn_mfma_f32_16x16x32_bf16(af0, pb0, z, 0, 0, 0);
        z = __builtin_amdgcn_mfma_f32_16x16x32_bf16(af1, pb1, z, 0, 0, 0);
        q = __builtin_amdgcn_mfma_f32_16x16x32_bf16(af0, pb2, q, 0, 0, 0);
        q = __builtin_amdgcn_mfma_f32_16x16x32_bf16(af1, pb3, q, 0, 0, 0);
        int c = n0 + row16;
        float bz = b1[c], bs = b3s[c];
#pragma unroll
        for (int i = 0; i < 4; i++) {
            int r = rq * 4 + i;
            int p = posw(r, c);
            float za = z[i] + bz;
            sZ[p] = f2bf(za);
            sY[p] = f2bf(za * za);
            sZ23[p] = f2bf(q[i] + bs);
        }
    }
    __syncthreads();

    // ---- P2: z1_2 = y1@W2a.T + b2a ; z2_2 = y1@W2b.T + b2b ; y2 -> sU
    {
        f32x4 aA = {0.f,0.f,0.f,0.f}, aB = {0.f,0.f,0.f,0.f};
        gemm_dualB<8, H, H>(sY, ws + O_W2ab + n0 * H, ws + O_W2bb + n0 * H, lane, aA, aB);
        int c = n0 + row16;
        float ba = b2a[c], bb = b2b[c];
#pragma unroll
        for (int i = 0; i < 4; i++) {
            int r = rq * 4 + i;
            int p = posw(r, c);
            float z12 = aA[i] + ba, z22 = aB[i] + bb;
            sZ12[p] = f2bf(z12);
            sZ22[p] = f2bf(z22);
            sU[p] = f2bf(z12 * z22);
        }
    }
    __syncthreads();

    // ---- P4: z1_3 = y2@W3a.T + b3a  AND  t = z2_3@(wout.w3a)T
    //          epilogue: y3 out, nb, sZ13 = z1_3, fold sZ12 *= t, sZ22 *= t
    {
        f32x4 zz = {0.f,0.f,0.f,0.f}, tt = {0.f,0.f,0.f,0.f};
        gemm_one<8, H, H>(sU, ws + O_W3ab + n0 * H, lane, 0, zz);
        gemm_one<8, H, H>(sZ23, ws + O_W3aT + n0 * H, lane, 0, tt);
        int c = n0 + row16;
        float ba = b3a[c], wo = wout[c];
#pragma unroll
        for (int i = 0; i < 4; i++) {
            int r = rq * 4 + i;
            int p = posw(r, c);
            float z13 = zz[i] + ba;
            float z23 = bf2f(sZ23[p]);
            float y3 = z13 * z23;
            out[Y_OFF + (R0 + r) * H + c] = y3;
            sZ13[p] = f2bf(z13);
            float t = tt[i];
            sZ12[p] = f2bf(t * bf2f(sZ12[p]));
            sZ22[p] = f2bf(t * bf2f(sZ22[p]));
            float v = wo * y3;
            v += __shfl_xor(v, 1);
            v += __shfl_xor(v, 2);
            v += __shfl_xor(v, 4);
            v += __shfl_xor(v, 8);
            if (row16 == 0) atomicAdd(&sNB[r], v);
        }
    }
    __syncthreads();

    // ---- P6: p = tz1@W2bT + tz2@W2aT ; c2 = 2*p*z (in place in sZ)
    {
        f32x4 pp = {0.f,0.f,0.f,0.f};
        gemm_one<8, H, H>(sZ12, ws + O_W2bT + n0 * H, lane, 0, pp);
        gemm_one<8, H, H>(sZ22, ws + O_W2aT + n0 * H, lane, 0, pp);
        int c = n0 + row16;
#pragma unroll
        for (int i = 0; i < 4; i++) {
            int r = rq * 4 + i;
            int p = posw(r, c);
            sZ[p] = f2bf(2.f * pp[i] * bf2f(sZ[p]));
        }
    }
    __syncthreads();

    // ---- P7: fj1 = z1_3@(wout.w3s)T, fj2 = c2@W1T; 2 mats x 4 ntiles x 2 K-halves
    {
        int mat = wid >> 3, kh = (wid >> 2) & 1, nt = wid & 3;
        const ushort_t* A = mat ? sZ : sZ13;
        const ushort_t* B = ws + (mat ? O_W1T : O_W3sT) + nt * 16 * H;
        f32x4 acc = {0.f,0.f,0.f,0.f};
        gemm_one<4, H, H>(A, B, lane, kh * 128, acc);
        // FJ partial buffers: [mat][kh] -> 4 x f32[16][64], aliased over sY/sU
        float* dst = mat ? ((float*)sU + kh * 1024) : ((float*)sY + kh * 1024);
        int c = nt * 16 + row16;
#pragma unroll
        for (int i = 0; i < 4; i++) dst[(rq * 4 + i) * 64 + c] = acc[i];
    }
    __syncthreads();

    // ---- P8: bdot + nb writes
    {
        float* F0 = (float*)sY;
        float* F1 = F0 + 1024;
        float* F2 = (float*)sU;
        float* F3 = F2 + 1024;
        int r = tid >> 6, j = tid & 63;
        int e = r * 64 + j;
        float s = (F0[e] + F1[e] + F2[e] + F3[e]) * sXd[e];
        s += __shfl_xor(s, 1);
        s += __shfl_xor(s, 2);
        s += __shfl_xor(s, 4);
        s += __shfl_xor(s, 8);
        s += __shfl_xor(s, 16);
        s += __shfl_xor(s, 32);
        if (j == 0) out[BDOT_OFF + R0 + r] = s;
        if (tid < RPB) out[NB_OFF + R0 + tid] = sNB[tid];
    }
}

extern "C" void kernel_launch(void* const* d_in, const int* in_sizes, int n_in,
                              void* d_out, int out_size, void* d_ws, size_t ws_size,
                              hipStream_t stream) {
    (void)in_sizes; (void)n_in; (void)out_size; (void)ws_size;
    const float* x = (const float*)d_in[0];
    const float* xd = (const float*)d_in[1];
    const float* w1 = (const float*)d_in[2];
    const float* b1 = (const float*)d_in[3];
    const float* w2a = (const float*)d_in[4];
    const float* b2a = (const float*)d_in[5];
    const float* w2b = (const float*)d_in[6];
    const float* b2b = (const float*)d_in[7];
    const float* w3a = (const float*)d_in[8];
    const float* b3a = (const float*)d_in[9];
    const float* w3s = (const float*)d_in[10];
    const float* b3s = (const float*)d_in[11];
    const float* wout = (const float*)d_in[12];
    const float* scalar = (const float*)d_in[13];
    ushort_t* ws = (ushort_t*)d_ws;
    float* out = (float*)d_out;

    prep_weights<<<56, 256, 0, stream>>>(w1, w2a, w2b, w3a, w3s, wout, ws);
    net_main<<<NBLK, 1024, 0, stream>>>(x, xd, b1, b2a, b2b, b3a, b3s, wout, scalar, ws, out);
}

// Round 6
// 33.287 us; speedup vs baseline: 1.5496x; 1.1776x over previous
//
#include <hip/hip_runtime.h>

typedef unsigned short ushort_t;
typedef unsigned int uint_t;
typedef __bf16 bf16x8 __attribute__((ext_vector_type(8)));
typedef float f32x4 __attribute__((ext_vector_type(4)));

#define H 256
#define RPB 16      // batch rows per block
#define NBLK 256    // 4096 / RPB

// output layout (f32): [nb 4096][bdot 4096][y 4096*256][yy 4096*64]
#define NB_OFF 0
#define BDOT_OFF 4096
#define Y_OFF 8192
#define YY_OFF (8192 + 4096 * 256)

__device__ __forceinline__ ushort_t f2bf(float x) {
    union { float f; uint_t u; } c; c.f = x;
    uint_t r = (c.u + 0x7FFFu + ((c.u >> 16) & 1u)) >> 16;  // RNE
    return (ushort_t)r;
}
__device__ __forceinline__ float bf2f(ushort_t v) {
    union { uint_t u; float f; } c; c.u = ((uint_t)v) << 16;
    return c.f;
}

// ws layout (ushort/bf16 units)
#define O_W1b  0        // [256][64]   orig (B for z)
#define O_W1T  16384    // [64][256]   W1T[i][g] = w1[g][i]
#define O_W2ab 32768    // [256][256]  orig
#define O_W2bb 98304
#define O_W3ab 163840
#define O_W2aT 229376   // [g][h] = w2a[h][g]
#define O_W2bT 294912
#define O_W3aT 360448   // [g][o] = wout[o]*w3a[o][g]   (wout folded)
#define O_W3sb 425984   // [256][64] orig
#define O_W3sT 442368   // [i][o] = wout[o]*w3s[o][i]   (wout folded)

__global__ __launch_bounds__(256) void prep_weights(
    const float* __restrict__ w1, const float* __restrict__ w2a,
    const float* __restrict__ w2b, const float* __restrict__ w3a,
    const float* __restrict__ w3s, const float* __restrict__ wout,
    ushort_t* __restrict__ ws) {
    __shared__ float tile[64][65];
    int b = blockIdx.x;
    const float* src; int Oo, Ot, R, C, t; bool scl;
    if (b < 16)      { src = w2a; Oo = O_W2ab; Ot = O_W2aT; R = 256; C = 256; t = b;      scl = false; }
    else if (b < 32) { src = w2b; Oo = O_W2bb; Ot = O_W2bT; R = 256; C = 256; t = b - 16; scl = false; }
    else if (b < 48) { src = w3a; Oo = O_W3ab; Ot = O_W3aT; R = 256; C = 256; t = b - 32; scl = true;  }
    else if (b < 52) { src = w1;  Oo = O_W1b;  Ot = O_W1T;  R = 256; C = 64;  t = b - 48; scl = false; }
    else             { src = w3s; Oo = O_W3sb; Ot = O_W3sT; R = 256; C = 64;  t = b - 52; scl = true;  }
    int tr, tc;
    if (C == 256) { tr = t >> 2; tc = t & 3; } else { tr = t; tc = 0; }
    int r0 = tr * 64, c0 = tc * 64;

    union pack8 { ushort_t u[8]; uint4 q; };
    for (int it = threadIdx.x; it < 512; it += 256) {
        int r = it >> 3, c8 = (it & 7) << 3;
        const float* s = src + (r0 + r) * C + c0 + c8;
        pack8 p;
#pragma unroll
        for (int j = 0; j < 8; j++) { float v = s[j]; tile[r][c8 + j] = v; p.u[j] = f2bf(v); }
        *(uint4*)(ws + Oo + (r0 + r) * C + c0 + c8) = p.q;
    }
    __syncthreads();
    for (int it = threadIdx.x; it < 512; it += 256) {
        int cc = it >> 3, r8 = (it & 7) << 3;
        pack8 p;
#pragma unroll
        for (int j = 0; j < 8; j++) {
            float v = tile[r8 + j][cc];
            if (scl) v *= wout[r0 + r8 + j];
            p.u[j] = f2bf(v);
        }
        *(uint4*)(ws + Ot + (c0 + cc) * R + r0 + r8) = p.q;
    }
}

// dynamic smem layout (ushort units)
#define U_BA   0        // staging mat0: [2][256*32] = 16384
#define U_BB   16384    // staging mat1
#define U_X    32768    // [16*64]
#define U_Z    33792    // [16*256] z -> c2
#define U_Y    37888    // y1; later FJ[0..1] (f32)
#define U_Z12  41984
#define U_Z22  46080
#define U_Z13  50176
#define U_Z23  54272
#define U_U    58368    // y2; later FJ[2..3] (f32)
#define U_XD   62464    // f32 [1024] (= 2048 ushorts... stored as f32[1024] = 2048 ushorts)
#define U_NB   66560    // f32 [16]
#define SMEM_USHORTS 66624
#define SMEM_BYTES (SMEM_USHORTS * 2)

__device__ __forceinline__ void gload16(const ushort_t* g, ushort_t* l) {
    __builtin_amdgcn_global_load_lds(
        (const __attribute__((address_space(1))) void*)g,
        (__attribute__((address_space(3))) void*)l, 16, 0, 0);
}

__device__ __forceinline__ int posw(int r, int c) { return r * H + (c ^ ((r & 7) << 3)); }

// Staged dual-matrix GEMM phase over K=256 in 8 chunks of 32, double-buffered
// LDS staging via global_load_lds (per-lane gather source, inverse-swizzled so
// linear LDS writes give the swizzled layout the ds_read side expects).
// Wave wid owns output n-tile [wid*16, wid*16+16). g0/g1: [256 n][256 k] bf16.
// A0/A1: LDS activations [16][256] col-XOR-swizzled. SUM: acc1 folds into acc0.
template <bool SUM>
__device__ __forceinline__ void staged_dual(
    const ushort_t* __restrict__ g0, const ushort_t* __restrict__ g1,
    const ushort_t* sA0, const ushort_t* sA1,
    ushort_t* sB0, ushort_t* sB1,
    int wid, int lane, f32x4& acc0, f32x4& acc1) {
    const int nsrc = (wid << 4) + (lane >> 2);       // staging row this lane fills
    const int osrc = ((lane & 3) ^ (nsrc & 3)) << 3; // inverse-swizzled k-octet
    const ushort_t* s0 = g0 + nsrc * 256 + osrc;
    const ushort_t* s1 = g1 + nsrc * 256 + osrc;
    const int dstb = wid << 9;                       // wave's 1KB slot (512 ushorts)
    const int row = lane & 15;
    const int nn = (wid << 4) + row;
    const int kq = (lane >> 4) << 3;
    const int boff = nn * 32 + (kq ^ ((nn & 3) << 3));
    const int sw = (row & 7) << 3;
    const ushort_t* a0p = sA0 + row * 256;
    const ushort_t* a1p = sA1 + row * 256;

    // prologue: stage chunk 0 into buffer 0
    gload16(s0, sB0 + dstb);
    gload16(s1, sB1 + dstb);
#pragma unroll
    for (int c = 0; c < 8; ++c) {
        if (c < 7) {
            int nb = ((c + 1) & 1) << 13;  // *8192
            gload16(s0 + (c + 1) * 32, sB0 + nb + dstb);
            gload16(s1 + (c + 1) * 32, sB1 + nb + dstb);
            asm volatile("s_waitcnt vmcnt(2)" ::: "memory");
        } else {
            asm volatile("s_waitcnt vmcnt(0)" ::: "memory");
        }
        __builtin_amdgcn_s_barrier();
        __builtin_amdgcn_sched_barrier(0);
        int cb = (c & 1) << 13;
        bf16x8 a0 = *(const bf16x8*)(a0p + (((c << 5) + kq) ^ sw));
        bf16x8 b0 = *(const bf16x8*)(sB0 + cb + boff);
        bf16x8 a1 = *(const bf16x8*)(a1p + (((c << 5) + kq) ^ sw));
        bf16x8 b1 = *(const bf16x8*)(sB1 + cb + boff);
        acc0 = __builtin_amdgcn_mfma_f32_16x16x32_bf16(a0, b0, acc0, 0, 0, 0);
        if (SUM)
            acc0 = __builtin_amdgcn_mfma_f32_16x16x32_bf16(a1, b1, acc0, 0, 0, 0);
        else
            acc1 = __builtin_amdgcn_mfma_f32_16x16x32_bf16(a1, b1, acc1, 0, 0, 0);
        __builtin_amdgcn_sched_barrier(0);
        __builtin_amdgcn_s_barrier();  // protect buffer about to be re-staged
    }
}

// register-path tile GEMM (small matrices), batched loads + sched fence
template <int NF, int STRA, int STRB>
__device__ __forceinline__ void gemm_one(const ushort_t* sA, const ushort_t* __restrict__ B0,
                                         int lane, int k0, f32x4& acc0) {
    const int row = lane & 15;
    const int kq = (lane >> 4) << 3;
    const int sw = (row & 7) << 3;
    bf16x8 b0[NF], a[NF];
    const ushort_t* bp0 = B0 + row * STRB + k0 + kq;
    const ushort_t* ap = sA + row * STRA;
#pragma unroll
    for (int i = 0; i < NF; i++) b0[i] = *(const bf16x8*)(bp0 + i * 32);
#pragma unroll
    for (int i = 0; i < NF; i++) a[i] = *(const bf16x8*)(ap + ((k0 + i * 32 + kq) ^ sw));
    __builtin_amdgcn_sched_barrier(0);
#pragma unroll
    for (int i = 0; i < NF; i++)
        acc0 = __builtin_amdgcn_mfma_f32_16x16x32_bf16(a[i], b0[i], acc0, 0, 0, 0);
}

__global__ __launch_bounds__(1024) void net_main(
    const float* __restrict__ x, const float* __restrict__ xd,
    const float* __restrict__ b1, const float* __restrict__ b2a,
    const float* __restrict__ b2b, const float* __restrict__ b3a,
    const float* __restrict__ b3s, const float* __restrict__ wout,
    const float* __restrict__ scalar, const ushort_t* __restrict__ ws,
    float* __restrict__ out) {
    extern __shared__ __align__(16) ushort_t smem[];
    ushort_t* sBA = smem + U_BA;
    ushort_t* sBB = smem + U_BB;
    ushort_t* sX  = smem + U_X;
    ushort_t* sZ  = smem + U_Z;
    ushort_t* sY  = smem + U_Y;
    ushort_t* sZ12 = smem + U_Z12;
    ushort_t* sZ22 = smem + U_Z22;
    ushort_t* sZ13 = smem + U_Z13;
    ushort_t* sZ23 = smem + U_Z23;
    ushort_t* sU  = smem + U_U;
    float* sXd = (float*)(smem + U_XD);
    float* sNB = (float*)(smem + U_NB);

    const int tid = threadIdx.x;
    const int wid = tid >> 6;     // 0..15
    const int lane = tid & 63;
    const int row16 = lane & 15;  // MFMA D column-within-tile
    const int rq = lane >> 4;     // MFMA D row = rq*4 + i
    const int R0 = blockIdx.x * RPB;
    const int n0 = wid * 16;      // this wave's 16-col tile
    const int row = lane & 15;
    const int kq = (lane >> 4) << 3;
    const int sw = (row & 7) << 3;

    // ---- P0: prefetch P1 B-fragments; stage x/xd; yy; zero nb
    bf16x8 pb0, pb1, pb2, pb3;
    {
        const ushort_t* w1p = ws + O_W1b + (n0 + row) * 64 + kq;
        const ushort_t* w3p = ws + O_W3sb + (n0 + row) * 64 + kq;
        pb0 = *(const bf16x8*)(w1p);
        pb1 = *(const bf16x8*)(w1p + 32);
        pb2 = *(const bf16x8*)(w3p);
        pb3 = *(const bf16x8*)(w3p + 32);
    }
    float sc = scalar[0];
    {
        int r = tid >> 6, c = tid & 63;  // 1024 threads = RPB*64 elements
        sX[r * 64 + (c ^ ((r & 7) << 3))] = f2bf(x[(R0 + r) * 64 + c]);
        sXd[tid] = xd[(R0 + r) * 64 + c];
        out[YY_OFF + (R0 + r) * 64 + c] = sc;
    }
    if (tid < RPB) sNB[tid] = 0.f;
    __syncthreads();

    // ---- P1: z = x@W1.T + b1 (y1 = z*z); z2_3 = x@W3s.T + b3s
    {
        bf16x8 af0 = *(const bf16x8*)(sX + row * 64 + (kq ^ sw));
        bf16x8 af1 = *(const bf16x8*)(sX + row * 64 + ((32 + kq) ^ sw));
        f32x4 z = {0.f,0.f,0.f,0.f}, q = {0.f,0.f,0.f,0.f};
        z = __builtin_amdgcn_mfma_f32_16x16x32_bf16(af0, pb0, z, 0, 0, 0);
        z = __builtin_amdgcn_mfma_f32_16x16x32_bf16(af1, pb1, z, 0, 0, 0);
        q = __builtin_amdgcn_mfma_f32_16x16x32_bf16(af0, pb2, q, 0, 0, 0);
        q = __builtin_amdgcn_mfma_f32_16x16x32_bf16(af1, pb3, q, 0, 0, 0);
        int c = n0 + row16;
        float bz = b1[c], bs = b3s[c];
#pragma unroll
        for (int i = 0; i < 4; i++) {
            int r = rq * 4 + i;
            int p = posw(r, c);
            float za = z[i] + bz;
            sZ[p] = f2bf(za);
            sY[p] = f2bf(za * za);
            sZ23[p] = f2bf(q[i] + bs);
        }
    }
    __syncthreads();

    // ---- P2 (staged): z1_2 = y1@W2a.T + b2a ; z2_2 = y1@W2b.T + b2b ; y2->sU
    {
        f32x4 aA = {0.f,0.f,0.f,0.f}, aB = {0.f,0.f,0.f,0.f};
        staged_dual<false>(ws + O_W2ab, ws + O_W2bb, sY, sY, sBA, sBB, wid, lane, aA, aB);
        int c = n0 + row16;
        float ba = b2a[c], bb = b2b[c];
#pragma unroll
        for (int i = 0; i < 4; i++) {
            int r = rq * 4 + i;
            int p = posw(r, c);
            float z12 = aA[i] + ba, z22 = aB[i] + bb;
            sZ12[p] = f2bf(z12);
            sZ22[p] = f2bf(z22);
            sU[p] = f2bf(z12 * z22);
        }
    }
    __syncthreads();

    // ---- P4 (staged): z1_3 = y2@W3a.T + b3a  AND  t = z2_3@(wout.w3a)T
    //       epilogue: y3 out, nb, sZ13 = z1_3, fold sZ12 *= t, sZ22 *= t
    {
        f32x4 zz = {0.f,0.f,0.f,0.f}, tt = {0.f,0.f,0.f,0.f};
        staged_dual<false>(ws + O_W3ab, ws + O_W3aT, sU, sZ23, sBA, sBB, wid, lane, zz, tt);
        int c = n0 + row16;
        float ba = b3a[c], wo = wout[c];
#pragma unroll
        for (int i = 0; i < 4; i++) {
            int r = rq * 4 + i;
            int p = posw(r, c);
            float z13 = zz[i] + ba;
            float z23 = bf2f(sZ23[p]);
            float y3 = z13 * z23;
            out[Y_OFF + (R0 + r) * H + c] = y3;
            sZ13[p] = f2bf(z13);
            float t = tt[i];
            sZ12[p] = f2bf(t * bf2f(sZ12[p]));
            sZ22[p] = f2bf(t * bf2f(sZ22[p]));
            float v = wo * y3;
            v += __shfl_xor(v, 1);
            v += __shfl_xor(v, 2);
            v += __shfl_xor(v, 4);
            v += __shfl_xor(v, 8);
            if (row16 == 0) atomicAdd(&sNB[r], v);
        }
    }
    __syncthreads();

    // ---- P6 (staged): p = tz1@W2bT + tz2@W2aT ; c2 = 2*p*z (in place in sZ)
    {
        f32x4 pp = {0.f,0.f,0.f,0.f}, dummy = {0.f,0.f,0.f,0.f};
        staged_dual<true>(ws + O_W2bT, ws + O_W2aT, sZ12, sZ22, sBA, sBB, wid, lane, pp, dummy);
        int c = n0 + row16;
#pragma unroll
        for (int i = 0; i < 4; i++) {
            int r = rq * 4 + i;
            int p = posw(r, c);
            sZ[p] = f2bf(2.f * pp[i] * bf2f(sZ[p]));
        }
    }
    __syncthreads();

    // ---- P7: fj1 = z1_3@(wout.w3s)T, fj2 = c2@W1T; 2 mats x 4 ntiles x 2 K-halves
    {
        int mat = wid >> 3, kh = (wid >> 2) & 1, nt = wid & 3;
        const ushort_t* A = mat ? sZ : sZ13;
        const ushort_t* B = ws + (mat ? O_W1T : O_W3sT) + nt * 16 * H;
        f32x4 acc = {0.f,0.f,0.f,0.f};
        gemm_one<4, H, H>(A, B, lane, kh * 128, acc);
        // FJ partial buffers: [mat][kh] -> 4 x f32[16][64], aliased over sY/sU
        float* dst = mat ? ((float*)sU + kh * 1024) : ((float*)sY + kh * 1024);
        int c = nt * 16 + row16;
#pragma unroll
        for (int i = 0; i < 4; i++) dst[(rq * 4 + i) * 64 + c] = acc[i];
    }
    __syncthreads();

    // ---- P8: bdot + nb writes
    {
        float* F0 = (float*)sY;
        float* F1 = F0 + 1024;
        float* F2 = (float*)sU;
        float* F3 = F2 + 1024;
        int r = tid >> 6, j = tid & 63;
        int e = r * 64 + j;
        float s = (F0[e] + F1[e] + F2[e] + F3[e]) * sXd[e];
        s += __shfl_xor(s, 1);
        s += __shfl_xor(s, 2);
        s += __shfl_xor(s, 4);
        s += __shfl_xor(s, 8);
        s += __shfl_xor(s, 16);
        s += __shfl_xor(s, 32);
        if (j == 0) out[BDOT_OFF + R0 + r] = s;
        if (tid < RPB) out[NB_OFF + R0 + tid] = sNB[tid];
    }
}

extern "C" void kernel_launch(void* const* d_in, const int* in_sizes, int n_in,
                              void* d_out, int out_size, void* d_ws, size_t ws_size,
                              hipStream_t stream) {
    (void)in_sizes; (void)n_in; (void)out_size; (void)ws_size;
    const float* x = (const float*)d_in[0];
    const float* xd = (const float*)d_in[1];
    const float* w1 = (const float*)d_in[2];
    const float* b1 = (const float*)d_in[3];
    const float* w2a = (const float*)d_in[4];
    const float* b2a = (const float*)d_in[5];
    const float* w2b = (const float*)d_in[6];
    const float* b2b = (const float*)d_in[7];
    const float* w3a = (const float*)d_in[8];
    const float* b3a = (const float*)d_in[9];
    const float* w3s = (const float*)d_in[10];
    const float* b3s = (const float*)d_in[11];
    const float* wout = (const float*)d_in[12];
    const float* scalar = (const float*)d_in[13];
    ushort_t* ws = (ushort_t*)d_ws;
    float* out = (float*)d_out;

    static bool attr_set = false;
    if (!attr_set) {
        hipFuncSetAttribute((const void*)net_main,
                            hipFuncAttributeMaxDynamicSharedMemorySize, SMEM_BYTES);
        attr_set = true;
    }

    prep_weights<<<56, 256, 0, stream>>>(w1, w2a, w2b, w3a, w3s, wout, ws);
    net_main<<<NBLK, 1024, SMEM_BYTES, stream>>>(x, xd, b1, b2a, b2b, b3a, b3s, wout, scalar, ws, out);
}

// Round 7
// 30.509 us; speedup vs baseline: 1.6907x; 1.0911x over previous
//
#include <hip/hip_runtime.h>

typedef unsigned short ushort_t;
typedef unsigned int uint_t;
typedef __bf16 bf16x8 __attribute__((ext_vector_type(8)));
typedef float f32x4 __attribute__((ext_vector_type(4)));

#define H 256
#define RPB 16      // batch rows per block
#define NBLK 256    // 4096 / RPB

// output layout (f32): [nb 4096][bdot 4096][y 4096*256][yy 4096*64]
#define NB_OFF 0
#define BDOT_OFF 4096
#define Y_OFF 8192
#define YY_OFF (8192 + 4096 * 256)

__device__ __forceinline__ ushort_t f2bf(float x) {
    union { float f; uint_t u; } c; c.f = x;
    uint_t r = (c.u + 0x7FFFu + ((c.u >> 16) & 1u)) >> 16;  // RNE
    return (ushort_t)r;
}
__device__ __forceinline__ float bf2f(ushort_t v) {
    union { uint_t u; float f; } c; c.u = ((uint_t)v) << 16;
    return c.f;
}

// ws layout (ushort/bf16 units)
#define O_W1b  0        // [256][64]   orig (B for z)
#define O_W1T  16384    // [64][256]   W1T[i][g] = w1[g][i]
#define O_W2ab 32768    // [256][256]  orig
#define O_W2bb 98304
#define O_W3ab 163840
#define O_W2aT 229376   // [g][h] = w2a[h][g]
#define O_W2bT 294912
#define O_W3aT 360448   // [g][o] = wout[o]*w3a[o][g]   (wout folded)
#define O_W3sb 425984   // [256][64] orig
#define O_W3sT 442368   // [i][o] = wout[o]*w3s[o][i]   (wout folded)

// 112 blocks, each converts one 32x64 tile into both layouts.
__global__ __launch_bounds__(256) void prep_weights(
    const float* __restrict__ w1, const float* __restrict__ w2a,
    const float* __restrict__ w2b, const float* __restrict__ w3a,
    const float* __restrict__ w3s, const float* __restrict__ wout,
    ushort_t* __restrict__ ws) {
    __shared__ float tile[32][65];
    int b = blockIdx.x;
    const float* src; int Oo, Ot, C, t; bool scl;
    if (b < 32)       { src = w2a; Oo = O_W2ab; Ot = O_W2aT; C = 256; t = b;       scl = false; }
    else if (b < 64)  { src = w2b; Oo = O_W2bb; Ot = O_W2bT; C = 256; t = b - 32;  scl = false; }
    else if (b < 96)  { src = w3a; Oo = O_W3ab; Ot = O_W3aT; C = 256; t = b - 64;  scl = true;  }
    else if (b < 104) { src = w1;  Oo = O_W1b;  Ot = O_W1T;  C = 64;  t = b - 96;  scl = false; }
    else              { src = w3s; Oo = O_W3sb; Ot = O_W3sT; C = 64;  t = b - 104; scl = true;  }
    int tr, tc;
    if (C == 256) { tr = t >> 2; tc = t & 3; } else { tr = t; tc = 0; }
    int r0 = tr * 32, c0 = tc * 64;
    const int tid = threadIdx.x;

    union pack8 { ushort_t u[8]; uint4 q; };
    {   // load 32x64 floats, store orig-layout bf16, keep f32 in LDS
        int r = tid >> 3, c8 = (tid & 7) << 3;
        const float* s = src + (r0 + r) * C + c0 + c8;
        pack8 p;
#pragma unroll
        for (int j = 0; j < 8; j++) { float v = s[j]; tile[r][c8 + j] = v; p.u[j] = f2bf(v); }
        *(uint4*)(ws + Oo + (r0 + r) * C + c0 + c8) = p.q;
    }
    __syncthreads();
    {   // transposed store (stride = 256 original rows), wout-scaled if scl
        int cc = tid >> 2, r8 = (tid & 3) << 3;
        pack8 p;
#pragma unroll
        for (int j = 0; j < 8; j++) {
            float v = tile[r8 + j][cc];
            if (scl) v *= wout[r0 + r8 + j];
            p.u[j] = f2bf(v);
        }
        *(uint4*)(ws + Ot + (c0 + cc) * 256 + r0 + r8) = p.q;
    }
}

// dynamic smem layout (ushort units)
#define U_BA   0        // staging mat0: [2 bufs][16 waves * 512]
#define U_BB   16384    // staging mat1
#define U_Z    32768    // [16*256] z -> c2
#define U_Y    36864    // y1; later FJ[0..1] (f32)
#define U_Z12  40960
#define U_Z22  45056
#define U_Z13  49152
#define U_Z23  53248
#define U_U    57344    // y2; later FJ[2..3] (f32)
#define U_XD   61440    // f32 [1024]
#define U_NB   63488    // f32 [16]
#define SMEM_USHORTS 63520
#define SMEM_BYTES (SMEM_USHORTS * 2)

__device__ __forceinline__ void gload16(const ushort_t* g, ushort_t* l) {
    __builtin_amdgcn_global_load_lds(
        (const __attribute__((address_space(1))) void*)g,
        (__attribute__((address_space(3))) void*)l, 16, 0, 0);
}

__device__ __forceinline__ int posw(int r, int c) { return r * H + (c ^ ((r & 7) << 3)); }

// Barrier-free staged dual-matrix GEMM over K=256, 8 chunks of 32, depth-2
// double-buffered DMA pipeline. Wave wid stages ONLY its own 1KB slots and
// reads ONLY those slots -> no cross-wave dependency, no s_barrier needed.
// g0/g1: [256 n][256 k] bf16. A0/A1: LDS activations [16][256] XOR-swizzled.
template <bool SUM>
__device__ __forceinline__ void staged_dual(
    const ushort_t* __restrict__ g0, const ushort_t* __restrict__ g1,
    const ushort_t* sA0, const ushort_t* sA1,
    ushort_t* sB0, ushort_t* sB1,
    int wid, int lane, f32x4& acc0, f32x4& acc1) {
    const int nsrc = (wid << 4) + (lane >> 2);       // staging row this lane fills
    const int osrc = ((lane & 3) ^ (nsrc & 3)) << 3; // inverse-swizzled k-octet
    const ushort_t* s0 = g0 + nsrc * 256 + osrc;
    const ushort_t* s1 = g1 + nsrc * 256 + osrc;
    const int dstb = wid << 9;                       // wave's 512-ushort slot
    const int row = lane & 15;
    const int nn = (wid << 4) + row;
    const int kq = (lane >> 4) << 3;
    const int boff = nn * 32 + (kq ^ ((nn & 3) << 3));
    const int sw = (row & 7) << 3;
    const ushort_t* a0p = sA0 + row * 256;
    const ushort_t* a1p = sA1 + row * 256;

    // clean vmcnt of any epilogue stores, then stage chunks 0 and 1
    asm volatile("s_waitcnt vmcnt(0)" ::: "memory");
    gload16(s0, sB0 + dstb);
    gload16(s1, sB1 + dstb);
    gload16(s0 + 32, sB0 + 8192 + dstb);
    gload16(s1 + 32, sB1 + 8192 + dstb);
#pragma unroll
    for (int c = 0; c < 8; ++c) {
        if (c < 7) asm volatile("s_waitcnt vmcnt(2)" ::: "memory");  // chunk c landed
        else       asm volatile("s_waitcnt vmcnt(0)" ::: "memory");
        const int cb = (c & 1) << 13;
        bf16x8 a0 = *(const bf16x8*)(a0p + (((c << 5) + kq) ^ sw));
        bf16x8 b0 = *(const bf16x8*)(sB0 + cb + boff);
        bf16x8 a1 = *(const bf16x8*)(a1p + (((c << 5) + kq) ^ sw));
        bf16x8 b1 = *(const bf16x8*)(sB1 + cb + boff);
        if (c < 6) {
            // slot (c&1) just read -> safe to re-stage chunk c+2 after lgkm drain
            asm volatile("s_waitcnt lgkmcnt(0)" ::: "memory");
            gload16(s0 + (c + 2) * 32, sB0 + cb + dstb);
            gload16(s1 + (c + 2) * 32, sB1 + cb + dstb);
        }
        acc0 = __builtin_amdgcn_mfma_f32_16x16x32_bf16(a0, b0, acc0, 0, 0, 0);
        if (SUM)
            acc0 = __builtin_amdgcn_mfma_f32_16x16x32_bf16(a1, b1, acc0, 0, 0, 0);
        else
            acc1 = __builtin_amdgcn_mfma_f32_16x16x32_bf16(a1, b1, acc1, 0, 0, 0);
    }
}

// register-path tile GEMM (small matrices), batched loads + sched fence
template <int NF, int STRA, int STRB>
__device__ __forceinline__ void gemm_one(const ushort_t* sA, const ushort_t* __restrict__ B0,
                                         int lane, int k0, f32x4& acc0) {
    const int row = lane & 15;
    const int kq = (lane >> 4) << 3;
    const int sw = (row & 7) << 3;
    bf16x8 b0[NF], a[NF];
    const ushort_t* bp0 = B0 + row * STRB + k0 + kq;
    const ushort_t* ap = sA + row * STRA;
#pragma unroll
    for (int i = 0; i < NF; i++) b0[i] = *(const bf16x8*)(bp0 + i * 32);
#pragma unroll
    for (int i = 0; i < NF; i++) a[i] = *(const bf16x8*)(ap + ((k0 + i * 32 + kq) ^ sw));
    __builtin_amdgcn_sched_barrier(0);
#pragma unroll
    for (int i = 0; i < NF; i++)
        acc0 = __builtin_amdgcn_mfma_f32_16x16x32_bf16(a[i], b0[i], acc0, 0, 0, 0);
}

__global__ __launch_bounds__(1024) void net_main(
    const float* __restrict__ x, const float* __restrict__ xd,
    const float* __restrict__ b1, const float* __restrict__ b2a,
    const float* __restrict__ b2b, const float* __restrict__ b3a,
    const float* __restrict__ b3s, const float* __restrict__ wout,
    const float* __restrict__ scalar, const ushort_t* __restrict__ ws,
    float* __restrict__ out) {
    extern __shared__ __align__(16) ushort_t smem[];
    ushort_t* sBA = smem + U_BA;
    ushort_t* sBB = smem + U_BB;
    ushort_t* sZ  = smem + U_Z;
    ushort_t* sY  = smem + U_Y;
    ushort_t* sZ12 = smem + U_Z12;
    ushort_t* sZ22 = smem + U_Z22;
    ushort_t* sZ13 = smem + U_Z13;
    ushort_t* sZ23 = smem + U_Z23;
    ushort_t* sU  = smem + U_U;
    float* sXd = (float*)(smem + U_XD);
    float* sNB = (float*)(smem + U_NB);

    const int tid = threadIdx.x;
    const int wid = tid >> 6;     // 0..15
    const int lane = tid & 63;
    const int row16 = lane & 15;  // MFMA D column-within-tile
    const int rq = lane >> 4;     // MFMA D row = rq*4 + i
    const int R0 = blockIdx.x * RPB;
    const int n0 = wid * 16;      // this wave's 16-col tile
    const int row = lane & 15;
    const int kq = (lane >> 4) << 3;
    const int sw = (row & 7) << 3;

    // ---- P1 (fused former P0): x direct from global f32 -> bf16 A-fragments;
    //      z = x@W1.T + b1 (y1 = z*z); z2_3 = x@W3s.T + b3s.
    {
        // B fragments (W1b, W3sb) — issue first, longest latency
        const ushort_t* w1p = ws + O_W1b + (n0 + row) * 64 + kq;
        const ushort_t* w3p = ws + O_W3sb + (n0 + row) * 64 + kq;
        bf16x8 pb0 = *(const bf16x8*)(w1p);
        bf16x8 pb1 = *(const bf16x8*)(w1p + 32);
        bf16x8 pb2 = *(const bf16x8*)(w3p);
        bf16x8 pb3 = *(const bf16x8*)(w3p + 32);
        // A fragments straight from global x (all waves share rows R0..R0+15)
        const float* xg = x + (R0 + row) * 64;
        float4 x0 = *(const float4*)(xg + kq);
        float4 x1 = *(const float4*)(xg + kq + 4);
        float4 x2 = *(const float4*)(xg + 32 + kq);
        float4 x3 = *(const float4*)(xg + 32 + kq + 4);
        // stage xd, yy, nb-init while loads are in flight
        float sc = scalar[0];
        {
            int r = tid >> 6, c = tid & 63;
            sXd[tid] = xd[(R0 + r) * 64 + c];
            out[YY_OFF + (R0 + r) * 64 + c] = sc;
            if (tid < RPB) sNB[tid] = 0.f;
        }
        union { ushort_t u[8]; bf16x8 v; } A0, A1;
#pragma unroll
        for (int j = 0; j < 4; j++) {
            A0.u[j]     = f2bf(((const float*)&x0)[j]);
            A0.u[4 + j] = f2bf(((const float*)&x1)[j]);
            A1.u[j]     = f2bf(((const float*)&x2)[j]);
            A1.u[4 + j] = f2bf(((const float*)&x3)[j]);
        }
        f32x4 z = {0.f,0.f,0.f,0.f}, q = {0.f,0.f,0.f,0.f};
        z = __builtin_amdgcn_mfma_f32_16x16x32_bf16(A0.v, pb0, z, 0, 0, 0);
        z = __builtin_amdgcn_mfma_f32_16x16x32_bf16(A1.v, pb1, z, 0, 0, 0);
        q = __builtin_amdgcn_mfma_f32_16x16x32_bf16(A0.v, pb2, q, 0, 0, 0);
        q = __builtin_amdgcn_mfma_f32_16x16x32_bf16(A1.v, pb3, q, 0, 0, 0);
        int c = n0 + row16;
        float bz = b1[c], bs = b3s[c];
#pragma unroll
        for (int i = 0; i < 4; i++) {
            int r = rq * 4 + i;
            int p = posw(r, c);
            float za = z[i] + bz;
            sZ[p] = f2bf(za);
            sY[p] = f2bf(za * za);
            sZ23[p] = f2bf(q[i] + bs);
        }
    }
    __syncthreads();

    // ---- P2 (staged): z1_2 = y1@W2a.T + b2a ; z2_2 = y1@W2b.T + b2b ; y2->sU
    {
        f32x4 aA = {0.f,0.f,0.f,0.f}, aB = {0.f,0.f,0.f,0.f};
        staged_dual<false>(ws + O_W2ab, ws + O_W2bb, sY, sY, sBA, sBB, wid, lane, aA, aB);
        int c = n0 + row16;
        float ba = b2a[c], bb = b2b[c];
#pragma unroll
        for (int i = 0; i < 4; i++) {
            int r = rq * 4 + i;
            int p = posw(r, c);
            float z12 = aA[i] + ba, z22 = aB[i] + bb;
            sZ12[p] = f2bf(z12);
            sZ22[p] = f2bf(z22);
            sU[p] = f2bf(z12 * z22);
        }
    }
    __syncthreads();

    // ---- P4 (staged): z1_3 = y2@W3a.T + b3a  AND  t = z2_3@(wout.w3a)T
    //       epilogue: y3 out, nb, sZ13 = z1_3, fold sZ12 *= t, sZ22 *= t
    {
        f32x4 zz = {0.f,0.f,0.f,0.f}, tt = {0.f,0.f,0.f,0.f};
        staged_dual<false>(ws + O_W3ab, ws + O_W3aT, sU, sZ23, sBA, sBB, wid, lane, zz, tt);
        int c = n0 + row16;
        float ba = b3a[c], wo = wout[c];
#pragma unroll
        for (int i = 0; i < 4; i++) {
            int r = rq * 4 + i;
            int p = posw(r, c);
            float z13 = zz[i] + ba;
            float z23 = bf2f(sZ23[p]);
            float y3 = z13 * z23;
            out[Y_OFF + (R0 + r) * H + c] = y3;
            sZ13[p] = f2bf(z13);
            float t = tt[i];
            sZ12[p] = f2bf(t * bf2f(sZ12[p]));
            sZ22[p] = f2bf(t * bf2f(sZ22[p]));
            float v = wo * y3;
            v += __shfl_xor(v, 1);
            v += __shfl_xor(v, 2);
            v += __shfl_xor(v, 4);
            v += __shfl_xor(v, 8);
            if (row16 == 0) atomicAdd(&sNB[r], v);
        }
    }
    __syncthreads();

    // ---- P6 (staged): p = tz1@W2bT + tz2@W2aT ; c2 = 2*p*z (in place in sZ)
    {
        f32x4 pp = {0.f,0.f,0.f,0.f}, dummy = {0.f,0.f,0.f,0.f};
        staged_dual<true>(ws + O_W2bT, ws + O_W2aT, sZ12, sZ22, sBA, sBB, wid, lane, pp, dummy);
        int c = n0 + row16;
#pragma unroll
        for (int i = 0; i < 4; i++) {
            int r = rq * 4 + i;
            int p = posw(r, c);
            sZ[p] = f2bf(2.f * pp[i] * bf2f(sZ[p]));
        }
    }
    __syncthreads();

    // ---- P7: fj1 = z1_3@(wout.w3s)T, fj2 = c2@W1T; 2 mats x 4 ntiles x 2 K-halves
    {
        int mat = wid >> 3, kh = (wid >> 2) & 1, nt = wid & 3;
        const ushort_t* A = mat ? sZ : sZ13;
        const ushort_t* B = ws + (mat ? O_W1T : O_W3sT) + nt * 16 * H;
        f32x4 acc = {0.f,0.f,0.f,0.f};
        gemm_one<4, H, H>(A, B, lane, kh * 128, acc);
        // FJ partial buffers: [mat][kh] -> 4 x f32[16][64], aliased over sY/sU
        float* dst = mat ? ((float*)sU + kh * 1024) : ((float*)sY + kh * 1024);
        int c = nt * 16 + row16;
#pragma unroll
        for (int i = 0; i < 4; i++) dst[(rq * 4 + i) * 64 + c] = acc[i];
    }
    __syncthreads();

    // ---- P8: bdot + nb writes
    {
        float* F0 = (float*)sY;
        float* F1 = F0 + 1024;
        float* F2 = (float*)sU;
        float* F3 = F2 + 1024;
        int r = tid >> 6, j = tid & 63;
        int e = r * 64 + j;
        float s = (F0[e] + F1[e] + F2[e] + F3[e]) * sXd[e];
        s += __shfl_xor(s, 1);
        s += __shfl_xor(s, 2);
        s += __shfl_xor(s, 4);
        s += __shfl_xor(s, 8);
        s += __shfl_xor(s, 16);
        s += __shfl_xor(s, 32);
        if (j == 0) out[BDOT_OFF + R0 + r] = s;
        if (tid < RPB) out[NB_OFF + R0 + tid] = sNB[tid];
    }
}

extern "C" void kernel_launch(void* const* d_in, const int* in_sizes, int n_in,
                              void* d_out, int out_size, void* d_ws, size_t ws_size,
                              hipStream_t stream) {
    (void)in_sizes; (void)n_in; (void)out_size; (void)ws_size;
    const float* x = (const float*)d_in[0];
    const float* xd = (const float*)d_in[1];
    const float* w1 = (const float*)d_in[2];
    const float* b1 = (const float*)d_in[3];
    const float* w2a = (const float*)d_in[4];
    const float* b2a = (const float*)d_in[5];
    const float* w2b = (const float*)d_in[6];
    const float* b2b = (const float*)d_in[7];
    const float* w3a = (const float*)d_in[8];
    const float* b3a = (const float*)d_in[9];
    const float* w3s = (const float*)d_in[10];
    const float* b3s = (const float*)d_in[11];
    const float* wout = (const float*)d_in[12];
    const float* scalar = (const float*)d_in[13];
    ushort_t* ws = (ushort_t*)d_ws;
    float* out = (float*)d_out;

    static bool attr_set = false;
    if (!attr_set) {
        hipFuncSetAttribute((const void*)net_main,
                            hipFuncAttributeMaxDynamicSharedMemorySize, SMEM_BYTES);
        attr_set = true;
    }

    prep_weights<<<112, 256, 0, stream>>>(w1, w2a, w2b, w3a, w3s, wout, ws);
    net_main<<<NBLK, 1024, SMEM_BYTES, stream>>>(x, xd, b1, b2a, b2b, b3a, b3s, wout, scalar, ws, out);
}